// Round 7
// baseline (144.704 us; speedup 1.0000x reference)
//
#include <hip/hip_runtime.h>
#include <hip/hip_bf16.h>
#include <hip/hip_fp16.h>

// R7 model (R3-R6 ablation): edge kernel is bound by VMEM INSTRUCTION SLOTS,
// not bytes (R6: FETCH halved, time unchanged), not ILP (R5 null), not VALU
// (R4: 1.9cyc/instr, only ~13us of 43). ~30us / 14 vmem/wave ~= 2.1us per
// gather-instruction slot. Lever: fewer gather instructions per edge.
// Change: concept tables -> ONE interleaved fp8 table ECB (row 256B; per
// 8-ch group: 8B cs | 8B ci) so each lane gets cs+ci in one dwordx4:
// conc loads 8->4, total vmem 14->10 per wave. fp8-conc accuracy proven in
// R3 (ALL tables fp8, absmax 0.0039). ESP/EIP stay fp8 (R6, absmax 0.0078).
// Edge per channel: sigma(a)-sigma(b) = (B-A)/(A*B), A=1+es*cs, B=1+ei*ci via
// v_pk_fma; fraction pair-tree 8->4->2->1 in F32 (v_fma_mix) -> 1 rcp/lane*k.
// 4 edges/wave, 32-bit addressing, DPP butterfly reduce — no LDS.
// Timed region: 2x 256MiB harness poison fills (~90us, structural) +
// edge + proj (~2us).
constexpr int EDGES = 250000;
constexpr int EMB   = 64;
constexpr int CNUM  = 128;
constexpr int NSTU  = 10000;
constexpr int NITEM = 50000;
constexpr int NCONC = 2048;

constexpr float NEG_LOG2E = -1.44269504088896340736f;

// proj job space: one wave per 16-row strip (conc strips: one wave per table)
constexpr int STU_JOBS  = NSTU  / 16;            // 625
constexpr int ITEM_JOBS = NITEM / 16;            // 3125
constexpr int CONC_JOBS = (NCONC / 16) * 2;      // 256
constexpr int NJOBS     = STU_JOBS + ITEM_JOBS + CONC_JOBS;  // 4006
constexpr int PROJ_BLKS = (NJOBS + 3) / 4;

typedef _Float16 h8 __attribute__((ext_vector_type(8)));
typedef _Float16 h4 __attribute__((ext_vector_type(4)));
typedef _Float16 h2 __attribute__((ext_vector_type(2)));
typedef float    f32x4 __attribute__((ext_vector_type(4)));
typedef float    f32x2 __attribute__((ext_vector_type(2)));

__device__ __forceinline__ h2 cvt2(float a, float b) {
#if __has_builtin(__builtin_amdgcn_cvt_pkrtz)
    return __builtin_bit_cast(h2, __builtin_amdgcn_cvt_pkrtz(a, b));
#else
    h2 r; r[0] = (_Float16)a; r[1] = (_Float16)b; return r;
#endif
}

__device__ __forceinline__ h8 pack8(float4 lo, float4 hi) {
    const h2 a = cvt2(lo.x, lo.y);
    const h2 b = cvt2(lo.z, lo.w);
    const h2 c = cvt2(hi.x, hi.y);
    const h2 d = cvt2(hi.z, hi.w);
    const h4 ab = __builtin_shufflevector(a, b, 0, 1, 2, 3);
    const h4 cd = __builtin_shufflevector(c, d, 0, 1, 2, 3);
    return __builtin_shufflevector(ab, cd, 0, 1, 2, 3, 4, 5, 6, 7);
}

// decode 8 fp8 e4m3 bytes -> h8 (R3/R6-proven byte order)
__device__ __forceinline__ h8 dec8(unsigned lo, unsigned hi) {
    const f32x2 a = __builtin_amdgcn_cvt_pk_f32_fp8(lo, false);
    const f32x2 b = __builtin_amdgcn_cvt_pk_f32_fp8(lo, true);
    const f32x2 c = __builtin_amdgcn_cvt_pk_f32_fp8(hi, false);
    const f32x2 d = __builtin_amdgcn_cvt_pk_f32_fp8(hi, true);
    const h2 h0 = cvt2(a[0], a[1]);
    const h2 h1 = cvt2(b[0], b[1]);
    const h2 h2v = cvt2(c[0], c[1]);
    const h2 h3 = cvt2(d[0], d[1]);
    const h4 lo4 = __builtin_shufflevector(h0, h1, 0, 1, 2, 3);
    const h4 hi4 = __builtin_shufflevector(h2v, h3, 0, 1, 2, 3);
    return __builtin_shufflevector(lo4, hi4, 0, 1, 2, 3, 4, 5, 6, 7);
}

// x += dpp-permuted x (full-rate VALU, no LDS pipe)
template <int CTRL>
__device__ __forceinline__ float dppadd(float x) {
    return x + __int_as_float(__builtin_amdgcn_update_dpp(
        0, __float_as_int(x), CTRL, 0xf, 0xf, true));
}

// ---- projection via MFMA: O[r,c] = exp(-dot(F[r,:], W[c, wcol:wcol+64])) ---
// stu/item -> flat fp8 rows (128B); conc -> interleaved fp8 ECB rows (256B).
__global__ __launch_bounds__(256) void proj_mfma(
        const float* __restrict__ stuF, const float* __restrict__ itemF,
        const float* __restrict__ concF,
        const float* __restrict__ W_stu, const float* __restrict__ W_item,
        const float* __restrict__ w_pred,
        unsigned char* __restrict__ ESP8, unsigned char* __restrict__ EIP8,
        unsigned char* __restrict__ ECB,
        _Float16* __restrict__ WH) {
    const int tid  = threadIdx.x;
    const int lane = tid & 63;
    const int job  = blockIdx.x * 4 + (tid >> 6);
    if (job >= NJOBS) return;

    if (job == 0) {  // one wave converts w_pred (128 f32) to fp16 once
        const float2 wv2 = ((const float2*)w_pred)[lane];
        h2 wh; wh[0] = (_Float16)wv2.x; wh[1] = (_Float16)wv2.y;
        *(h2*)(WH + 2 * lane) = wh;
    }

    const float* F; const float* W; unsigned char* O8;
    int strip, wcol, sel = 0; bool isconc;
    if (job < STU_JOBS) {
        F = stuF;  W = W_stu;  O8 = ESP8; strip = job; wcol = 0;
        isconc = false;
    } else if (job < STU_JOBS + ITEM_JOBS) {
        F = itemF; W = W_item; O8 = EIP8; strip = job - STU_JOBS; wcol = 0;
        isconc = false;
    } else {
        const int g = job - STU_JOBS - ITEM_JOBS;
        F = concF; W = (g & 1) ? W_item : W_stu; O8 = ECB;
        sel = g & 1; strip = g >> 1; wcol = EMB; isconc = true;
    }

    const int m = lane & 15;       // A row / B channel / D col
    const int q = lane >> 4;       // quad
    const int row = strip * 16 + m;

    const float4* fa = (const float4*)(F + (size_t)row * EMB + q * 8);
    const float4* fb = (const float4*)(F + (size_t)row * EMB + 32 + q * 8);
    const h8 A0 = pack8(fa[0], fa[1]);
    const h8 A1 = pack8(fb[0], fb[1]);

    const int orow = strip * 16 + q * 4;

#pragma unroll
    for (int ct = 0; ct < 8; ++ct) {
        const int ch = ct * 16 + m;
        const float* wr = W + (size_t)ch * (2 * EMB) + wcol;
        const float4* wb0 = (const float4*)(wr + q * 8);
        const float4* wb1 = (const float4*)(wr + 32 + q * 8);
        const h8 B0 = pack8(wb0[0], wb0[1]);
        const h8 B1 = pack8(wb1[0], wb1[1]);

        f32x4 acc = {0.f, 0.f, 0.f, 0.f};
        acc = __builtin_amdgcn_mfma_f32_16x16x32_f16(A0, B0, acc, 0, 0, 0);
        acc = __builtin_amdgcn_mfma_f32_16x16x32_f16(A1, B1, acc, 0, 0, 0);

#pragma unroll
        for (int r = 0; r < 4; ++r) {
            const float e = __builtin_amdgcn_exp2f(acc[r] * NEG_LOG2E);
            const int pk = __builtin_amdgcn_cvt_pk_fp8_f32(e, e, 0, false);
            unsigned off;
            if (!isconc) {
                off = (unsigned)(orow + r) * CNUM + (unsigned)ch;
            } else {
                // interleaved row: group (ch>>3) at 16B; [cs 8B | ci 8B]
                off = (unsigned)(orow + r) * (2 * CNUM)
                    + (((unsigned)ch >> 3) << 4) + ((unsigned)sel << 3)
                    + ((unsigned)ch & 7);
            }
            O8[off] = (unsigned char)(pk & 0xff);
        }
    }
}

__device__ __forceinline__ float sigm(float x) {
    return __builtin_amdgcn_rcpf(1.f + __builtin_amdgcn_exp2f(x * NEG_LOG2E));
}

// ---- edge phase: 4 edges/wave, 16 lanes/edge, lane owns 8 channels --------
__global__ __launch_bounds__(256) void edge_kernel(
        const int*  __restrict__ stu_idx,
        const int*  __restrict__ item_idx,
        const int4* __restrict__ conc_idx,
        const unsigned char* __restrict__ ESP8,
        const unsigned char* __restrict__ EIP8,
        const unsigned char* __restrict__ ECB,
        const _Float16* __restrict__ WH,
        const float* __restrict__ b_pred,
        float* __restrict__ out) {
    const int lane = threadIdx.x & 63;
    const int wvg  = (blockIdx.x * blockDim.x + threadIdx.x) >> 6;
    const int sub  = lane >> 4;      // edge within wave 0..3
    const int li   = lane & 15;      // lane within edge; owns ch li*8..li*8+7
    const int e    = wvg * 4 + sub;  // grid sized exactly
    const unsigned co = (unsigned)(li * 8);   // 8 channels

    const int s  = stu_idx[e];
    const int it = item_idx[e];
    const int4 c4 = conc_idx[e];

    // fp8 rows: byte offset = idx*128 + li*8
    const uint2 vs8 = *(const uint2*)(ESP8 + (((unsigned)s  << 7) + co));
    const uint2 vi8 = *(const uint2*)(EIP8 + (((unsigned)it << 7) + co));
    const h8 es = dec8(vs8.x, vs8.y);
    const h8 ei = dec8(vi8.x, vi8.y);
    const h8 w8 = *(const h8*)(WH + co);
    const float b = b_pred[0];

    const _Float16 O1 = (_Float16)1.f;
    const h8 ONE = {O1, O1, O1, O1, O1, O1, O1, O1};

    const int ck[4] = {c4.x, c4.y, c4.z, c4.w};
    float p[4];
#pragma unroll
    for (int k = 0; k < 4; ++k) {
        // ONE dwordx4 per k: 8B cs + 8B ci, interleaved row of 256B
        const uint4 vv = *(const uint4*)(ECB + (((unsigned)ck[k] << 8)
                                               + (co << 1)));
        const h8 cs = dec8(vv.x, vv.y);
        const h8 ci = dec8(vv.z, vv.w);
        const h8 Aq = es * cs + ONE;       // 1+t        (v_pk_fma)
        const h8 Bq = ei * ci + ONE;       // 1+u        (v_pk_fma)
        const h8 dn = Aq * Bq;             // den, <=65504 till ~12-sigma
        const h8 nm = w8 * (Bq - Aq);      // w*(u-t)
        // pair-tree in F32 (v_fma_mix reads fp16 ops directly): 8->4->2->1
        float N1[4], D1[4];
#pragma unroll
        for (int i = 0; i < 4; ++i) {
            N1[i] = (float)nm[i] * (float)dn[i + 4]
                  + (float)nm[i + 4] * (float)dn[i];
            D1[i] = (float)dn[i] * (float)dn[i + 4];
        }
        const float N2a = N1[0] * D1[2] + N1[2] * D1[0];
        const float N2b = N1[1] * D1[3] + N1[3] * D1[1];
        const float D2a = D1[0] * D1[2];
        const float D2b = D1[1] * D1[3];
        const float N3 = N2a * D2b + N2b * D2a;
        const float D3 = D2a * D2b;        // prod of 8 dens; f32-safe
        p[k] = N3 * __builtin_amdgcn_rcpf(D3);
    }

    // 16-lane sum via DPP butterfly; xor-basis {1,2,7,15} spans the group.
#pragma unroll
    for (int j = 0; j < 4; ++j) p[j] = dppadd<0xB1>(p[j]);   // quad_perm xor1
#pragma unroll
    for (int j = 0; j < 4; ++j) p[j] = dppadd<0x4E>(p[j]);   // quad_perm xor2
#pragma unroll
    for (int j = 0; j < 4; ++j) p[j] = dppadd<0x141>(p[j]);  // row_half_mirror
#pragma unroll
    for (int j = 0; j < 4; ++j) p[j] = dppadd<0x140>(p[j]);  // row_mirror

    const float r = 0.25f * (sigm(p[0] + b) + sigm(p[1] + b) +
                             sigm(p[2] + b) + sigm(p[3] + b));
    if (li == 0) out[e] = r;
}

extern "C" void kernel_launch(void* const* d_in, const int* in_sizes, int n_in,
                              void* d_out, int out_size, void* d_ws, size_t ws_size,
                              hipStream_t stream) {
    const int* stu_idx  = (const int*)d_in[0];
    const int* item_idx = (const int*)d_in[1];
    const int* conc_idx = (const int*)d_in[2];
    const float* stu_fusion     = (const float*)d_in[3];
    const float* item_fusion    = (const float*)d_in[4];
    const float* concept_fusion = (const float*)d_in[5];
    const float* W_stu          = (const float*)d_in[6];
    const float* W_item         = (const float*)d_in[7];
    const float* w_pred         = (const float*)d_in[8];
    const float* b_pred         = (const float*)d_in[9];
    float* out = (float*)d_out;

    // workspace: ESP8(u8) | EIP8(u8) | ECB(u8, interleaved cs/ci) | WH(f16)
    unsigned char* ESP8 = (unsigned char*)d_ws;
    unsigned char* EIP8 = ESP8 + (size_t)NSTU * CNUM;
    unsigned char* ECB  = EIP8 + (size_t)NITEM * CNUM;
    _Float16* WH = (_Float16*)(ECB + (size_t)NCONC * 2 * CNUM);

    proj_mfma<<<PROJ_BLKS, 256, 0, stream>>>(
        stu_fusion, item_fusion, concept_fusion, W_stu, W_item, w_pred,
        ESP8, EIP8, ECB, WH);

    edge_kernel<<<EDGES / 16, 256, 0, stream>>>(
        stu_idx, item_idx, (const int4*)conc_idx,
        ESP8, EIP8, ECB, WH, b_pred, out);
}

// Round 8
// 136.920 us; speedup vs baseline: 1.0569x; 1.0569x over previous
//
#include <hip/hip_runtime.h>
#include <hip/hip_bf16.h>
#include <hip/hip_fp16.h>

// R8 = revert to R4 (best verified: edge 43.3us, absmax 0.0039, total 135.8).
// Final model (R3-R7 ablation ledger):
//   - edge is VALU-ISSUE BOUND (VALUBusy 75-80% per-SIMD): instr count is
//     the only lever that ever moved time (R3->R4 -3.1us; R6->R7 +6.2us).
//   - FETCH bytes null (R6: halved, time unchanged). vmem slots/lines null
//     (R7: -29% slots, -50% lines, zero gain). ILP null (R5).
//   - fp8 decode costs ~0.8us per dec8 chain (measured twice) > any memory
//     gain -> all tables fp16.
//   - front-end (Aq,Bq,dn,delta,nm = 20 instr/k) and f32 pair-tree (23/k)
//     are near-minimal; fp16 tree levels infeasible (alpha range empty for
//     12-sigma den tails — R1 NaN lesson).
// Timed region: 2x 256MiB harness poison fills ~90us (structural) +
// edge ~43us (VALU floor) + proj ~2us.
constexpr int EDGES = 250000;
constexpr int EMB   = 64;
constexpr int CNUM  = 128;
constexpr int NSTU  = 10000;
constexpr int NITEM = 50000;
constexpr int NCONC = 2048;

constexpr float NEG_LOG2E = -1.44269504088896340736f;

// proj job space: one wave per 16-row strip (conc strips: one wave per table)
constexpr int STU_JOBS  = NSTU  / 16;            // 625
constexpr int ITEM_JOBS = NITEM / 16;            // 3125
constexpr int CONC_JOBS = (NCONC / 16) * 2;      // 256
constexpr int NJOBS     = STU_JOBS + ITEM_JOBS + CONC_JOBS;  // 4006
constexpr int PROJ_BLKS = (NJOBS + 3) / 4;

typedef _Float16 h8 __attribute__((ext_vector_type(8)));
typedef _Float16 h4 __attribute__((ext_vector_type(4)));
typedef _Float16 h2 __attribute__((ext_vector_type(2)));
typedef float    f32x4 __attribute__((ext_vector_type(4)));

__device__ __forceinline__ h2 cvt2(float a, float b) {
#if __has_builtin(__builtin_amdgcn_cvt_pkrtz)
    return __builtin_bit_cast(h2, __builtin_amdgcn_cvt_pkrtz(a, b));
#else
    h2 r; r[0] = (_Float16)a; r[1] = (_Float16)b; return r;
#endif
}

__device__ __forceinline__ h8 pack8(float4 lo, float4 hi) {
    const h2 a = cvt2(lo.x, lo.y);
    const h2 b = cvt2(lo.z, lo.w);
    const h2 c = cvt2(hi.x, hi.y);
    const h2 d = cvt2(hi.z, hi.w);
    const h4 ab = __builtin_shufflevector(a, b, 0, 1, 2, 3);
    const h4 cd = __builtin_shufflevector(c, d, 0, 1, 2, 3);
    return __builtin_shufflevector(ab, cd, 0, 1, 2, 3, 4, 5, 6, 7);
}

// x += dpp-permuted x (full-rate VALU, no LDS pipe)
template <int CTRL>
__device__ __forceinline__ float dppadd(float x) {
    return x + __int_as_float(__builtin_amdgcn_update_dpp(
        0, __float_as_int(x), CTRL, 0xf, 0xf, true));
}

// ---- projection via MFMA: O[r,c] = exp(-dot(F[r,:], W[c, wcol:wcol+64])) ---
__global__ __launch_bounds__(256) void proj_mfma(
        const float* __restrict__ stuF, const float* __restrict__ itemF,
        const float* __restrict__ concF,
        const float* __restrict__ W_stu, const float* __restrict__ W_item,
        const float* __restrict__ w_pred,
        _Float16* __restrict__ ESP, _Float16* __restrict__ EIP,
        _Float16* __restrict__ ECS, _Float16* __restrict__ ECI,
        _Float16* __restrict__ WH) {
    const int tid  = threadIdx.x;
    const int lane = tid & 63;
    const int job  = blockIdx.x * 4 + (tid >> 6);
    if (job >= NJOBS) return;

    if (job == 0) {  // one wave converts w_pred (128 f32) to fp16 once
        const float2 wv2 = ((const float2*)w_pred)[lane];
        h2 wh; wh[0] = (_Float16)wv2.x; wh[1] = (_Float16)wv2.y;
        *(h2*)(WH + 2 * lane) = wh;
    }

    const float* F; const float* W; _Float16* O; int strip, wcol;
    if (job < STU_JOBS) {
        F = stuF;  W = W_stu;  O = ESP; strip = job; wcol = 0;
    } else if (job < STU_JOBS + ITEM_JOBS) {
        F = itemF; W = W_item; O = EIP; strip = job - STU_JOBS; wcol = 0;
    } else {
        const int g = job - STU_JOBS - ITEM_JOBS;
        F = concF; W = (g & 1) ? W_item : W_stu; O = (g & 1) ? ECI : ECS;
        strip = g >> 1; wcol = EMB;
    }

    const int m = lane & 15;       // A row / B channel / D col
    const int q = lane >> 4;       // quad
    const int row = strip * 16 + m;

    const float4* fa = (const float4*)(F + (size_t)row * EMB + q * 8);
    const float4* fb = (const float4*)(F + (size_t)row * EMB + 32 + q * 8);
    const h8 A0 = pack8(fa[0], fa[1]);
    const h8 A1 = pack8(fb[0], fb[1]);

    const int orow = strip * 16 + q * 4;

#pragma unroll
    for (int ct = 0; ct < 8; ++ct) {
        const int ch = ct * 16 + m;
        const float* wr = W + (size_t)ch * (2 * EMB) + wcol;
        const float4* wb0 = (const float4*)(wr + q * 8);
        const float4* wb1 = (const float4*)(wr + 32 + q * 8);
        const h8 B0 = pack8(wb0[0], wb0[1]);
        const h8 B1 = pack8(wb1[0], wb1[1]);

        f32x4 acc = {0.f, 0.f, 0.f, 0.f};
        acc = __builtin_amdgcn_mfma_f32_16x16x32_f16(A0, B0, acc, 0, 0, 0);
        acc = __builtin_amdgcn_mfma_f32_16x16x32_f16(A1, B1, acc, 0, 0, 0);

#pragma unroll
        for (int r = 0; r < 4; ++r) {
            const float e = __builtin_amdgcn_exp2f(acc[r] * NEG_LOG2E);
            O[(unsigned)(orow + r) * CNUM + ct * 16 + m] = (_Float16)e;
        }
    }
}

__device__ __forceinline__ float sigm(float x) {
    return __builtin_amdgcn_rcpf(1.f + __builtin_amdgcn_exp2f(x * NEG_LOG2E));
}

// ---- edge phase: 4 edges/wave, 16 lanes/edge, lane owns 8 channels --------
__global__ __launch_bounds__(256) void edge_kernel(
        const int*  __restrict__ stu_idx,
        const int*  __restrict__ item_idx,
        const int4* __restrict__ conc_idx,
        const _Float16* __restrict__ ESP,
        const _Float16* __restrict__ EIP,
        const _Float16* __restrict__ ECS,
        const _Float16* __restrict__ ECI,
        const _Float16* __restrict__ WH,
        const float* __restrict__ b_pred,
        float* __restrict__ out) {
    const int lane = threadIdx.x & 63;
    const int wvg  = (blockIdx.x * blockDim.x + threadIdx.x) >> 6;
    const int sub  = lane >> 4;      // edge within wave 0..3
    const int li   = lane & 15;      // lane within edge; owns ch li*8..li*8+7
    const int e    = wvg * 4 + sub;  // grid sized exactly
    const unsigned co = (unsigned)(li * 8);

    const int s  = stu_idx[e];
    const int it = item_idx[e];
    const int4 c4 = conc_idx[e];

    // 32-bit offsets: idx*128 + li*8; SGPR base + VGPR voffset addressing.
    const h8 es = *(const h8*)(ESP + (((unsigned)s  << 7) + co));
    const h8 ei = *(const h8*)(EIP + (((unsigned)it << 7) + co));
    const h8 w8 = *(const h8*)(WH + co);
    const float b = b_pred[0];

    const _Float16 O1 = (_Float16)1.f;
    const h8 ONE = {O1, O1, O1, O1, O1, O1, O1, O1};

    const int ck[4] = {c4.x, c4.y, c4.z, c4.w};
    float p[4];
#pragma unroll
    for (int k = 0; k < 4; ++k) {
        const unsigned off = ((unsigned)ck[k] << 7) + co;
        const h8 cs = *(const h8*)(ECS + off);
        const h8 ci = *(const h8*)(ECI + off);
        const h8 Aq = es * cs + ONE;       // 1+t        (v_pk_fma)
        const h8 Bq = ei * ci + ONE;       // 1+u        (v_pk_fma)
        const h8 dn = Aq * Bq;             // den, <=65504 till ~12-sigma
        const h8 nm = w8 * (Bq - Aq);      // w*(u-t)
        // pair-tree in F32 (v_fma_mix reads fp16 ops directly): 8->4->2->1
        float N1[4], D1[4];
#pragma unroll
        for (int i = 0; i < 4; ++i) {
            N1[i] = (float)nm[i] * (float)dn[i + 4]
                  + (float)nm[i + 4] * (float)dn[i];
            D1[i] = (float)dn[i] * (float)dn[i + 4];
        }
        const float N2a = N1[0] * D1[2] + N1[2] * D1[0];
        const float N2b = N1[1] * D1[3] + N1[3] * D1[1];
        const float D2a = D1[0] * D1[2];
        const float D2b = D1[1] * D1[3];
        const float N3 = N2a * D2b + N2b * D2a;
        const float D3 = D2a * D2b;        // prod of 8 dens; f32-safe
        p[k] = N3 * __builtin_amdgcn_rcpf(D3);
    }

    // 16-lane sum via DPP butterfly; xor-basis {1,2,7,15} spans the group.
#pragma unroll
    for (int j = 0; j < 4; ++j) p[j] = dppadd<0xB1>(p[j]);   // quad_perm xor1
#pragma unroll
    for (int j = 0; j < 4; ++j) p[j] = dppadd<0x4E>(p[j]);   // quad_perm xor2
#pragma unroll
    for (int j = 0; j < 4; ++j) p[j] = dppadd<0x141>(p[j]);  // row_half_mirror
#pragma unroll
    for (int j = 0; j < 4; ++j) p[j] = dppadd<0x140>(p[j]);  // row_mirror

    const float r = 0.25f * (sigm(p[0] + b) + sigm(p[1] + b) +
                             sigm(p[2] + b) + sigm(p[3] + b));
    if (li == 0) out[e] = r;
}

extern "C" void kernel_launch(void* const* d_in, const int* in_sizes, int n_in,
                              void* d_out, int out_size, void* d_ws, size_t ws_size,
                              hipStream_t stream) {
    const int* stu_idx  = (const int*)d_in[0];
    const int* item_idx = (const int*)d_in[1];
    const int* conc_idx = (const int*)d_in[2];
    const float* stu_fusion     = (const float*)d_in[3];
    const float* item_fusion    = (const float*)d_in[4];
    const float* concept_fusion = (const float*)d_in[5];
    const float* W_stu          = (const float*)d_in[6];
    const float* W_item         = (const float*)d_in[7];
    const float* w_pred         = (const float*)d_in[8];
    const float* b_pred         = (const float*)d_in[9];
    float* out = (float*)d_out;

    // workspace (_Float16): ESP | EIP | ECS | ECI | WH
    _Float16* ESP = (_Float16*)d_ws;
    _Float16* EIP = ESP + (size_t)NSTU * CNUM;
    _Float16* ECS = EIP + (size_t)NITEM * CNUM;
    _Float16* ECI = ECS + (size_t)NCONC * CNUM;
    _Float16* WH  = ECI + (size_t)NCONC * CNUM;

    proj_mfma<<<PROJ_BLKS, 256, 0, stream>>>(
        stu_fusion, item_fusion, concept_fusion, W_stu, W_item, w_pred,
        ESP, EIP, ECS, ECI, WH);

    edge_kernel<<<EDGES / 16, 256, 0, stream>>>(
        stu_idx, item_idx, (const int4*)conc_idx,
        ESP, EIP, ECS, ECI, WH, b_pred, out);
}